// Round 4
// baseline (670.244 us; speedup 1.0000x reference)
//
#include <hip/hip_runtime.h>

// ---------------------------------------------------------------------------
// 2-layer GAT + classifier, CSR-based (no float atomics).
// Layout: features 128-wide both layers, 4 heads x 32 channels.
// Softmax max-subtraction dropped (shift-invariant; logits provably < 20
// for glorot-scaled weights and N(0,1) inputs -> exp() cannot overflow fp32).
// ---------------------------------------------------------------------------

__device__ __forceinline__ float leaky02(float v) { return v > 0.f ? v : 0.2f * v; }

// ---------------- CSR build ----------------
__global__ void k_hist(const int* __restrict__ ei, int* __restrict__ deg, int E, int N) {
  int i = blockIdx.x * blockDim.x + threadIdx.x;
  if (i >= E + N) return;
  int d = (i < E) ? ei[E + i] : (i - E);   // self-loop for i >= E
  atomicAdd(&deg[d], 1);
}

__global__ void k_partial(const int* __restrict__ deg, int* __restrict__ part, int N) {
  int base = blockIdx.x * 2048;
  int t = threadIdx.x;
  int s = 0;
#pragma unroll
  for (int i = 0; i < 8; ++i) {
    int idx = base + i * 256 + t;
    if (idx < N) s += deg[idx];
  }
  for (int off = 32; off; off >>= 1) s += __shfl_xor(s, off);
  __shared__ int ps[4];
  if ((t & 63) == 0) ps[t >> 6] = s;
  __syncthreads();
  if (t == 0) part[blockIdx.x] = ps[0] + ps[1] + ps[2] + ps[3];
}

__global__ void k_scan_part(const int* __restrict__ part, int* __restrict__ choff,
                            int* __restrict__ rowptr, int nchunk, int N) {
  if (threadIdx.x == 0) {
    int run = 0;
    for (int i = 0; i < nchunk; ++i) { choff[i] = run; run += part[i]; }
    rowptr[N] = run;
  }
}

__global__ void k_scan_final(const int* __restrict__ deg, const int* __restrict__ choff,
                             int* __restrict__ rowptr, int N) {
  int base = blockIdx.x * 2048;
  int t = threadIdx.x;
  int vals[8];
  int s = 0;
#pragma unroll
  for (int i = 0; i < 8; ++i) {
    int idx = base + t * 8 + i;
    int v = (idx < N) ? deg[idx] : 0;
    vals[i] = s;
    s += v;
  }
  __shared__ int lds[256];
  lds[t] = s;
  __syncthreads();
  for (int off = 1; off < 256; off <<= 1) {
    int v = (t >= off) ? lds[t - off] : 0;
    __syncthreads();
    lds[t] += v;
    __syncthreads();
  }
  int excl = lds[t] - s + choff[blockIdx.x];
#pragma unroll
  for (int i = 0; i < 8; ++i) {
    int idx = base + t * 8 + i;
    if (idx < N) rowptr[idx] = excl + vals[i];
  }
}

__global__ void k_scatter(const int* __restrict__ ei, const int* __restrict__ rowptr,
                          int* __restrict__ fill, int* __restrict__ colsrc, int E, int N) {
  int i = blockIdx.x * blockDim.x + threadIdx.x;
  if (i >= E + N) return;
  int s, d;
  if (i < E) { s = ei[i]; d = ei[E + i]; } else { s = i - E; d = s; }
  int pos = rowptr[d] + atomicAdd(&fill[d], 1);
  colsrc[pos] = s;
}

// ---------------- fp32 GEMM: C[nrows,128] = A[nrows,128] @ W[128,128] ----------------
// 64x64 tile per block (grid.y = 2 column halves), 256 threads, 4x4 per thread.
__global__ __launch_bounds__(256) void k_gemm128(const float* __restrict__ A,
                                                 const float* __restrict__ W,
                                                 float* __restrict__ C, int nrows) {
  __shared__ float sA[16][68];  // [k][m]; stride 68 -> sA writes are 2-way (free)
  __shared__ float sB[16][68];  // [k][c]
  const int t = threadIdx.x;
  const int row0 = blockIdx.x * 64;
  const int col0 = blockIdx.y * 64;
  const int tx = t & 15, ty = t >> 4;
  float acc[4][4] = {{0.f, 0.f, 0.f, 0.f}, {0.f, 0.f, 0.f, 0.f},
                     {0.f, 0.f, 0.f, 0.f}, {0.f, 0.f, 0.f, 0.f}};
  for (int kc = 0; kc < 128; kc += 16) {
    {  // A-tile: 64 rows x 16 k, one float4 per thread
      int m = t >> 2;
      int k4 = (t & 3) * 4;
      int row = row0 + m;
      float4 a = (row < nrows) ? *(const float4*)&A[row * 128 + kc + k4]
                               : make_float4(0.f, 0.f, 0.f, 0.f);
      sA[k4 + 0][m] = a.x;
      sA[k4 + 1][m] = a.y;
      sA[k4 + 2][m] = a.z;
      sA[k4 + 3][m] = a.w;
    }
    {  // B-tile: 16 k x 64 cols, one float4 per thread
      int kk = t >> 4;
      int c4 = (t & 15) * 4;
      float4 b = *(const float4*)&W[(kc + kk) * 128 + col0 + c4];
      *(float4*)&sB[kk][c4] = b;
    }
    __syncthreads();
#pragma unroll
    for (int k = 0; k < 16; ++k) {
      const float4 a = *(const float4*)&sA[k][ty * 4];
      const float4 b = *(const float4*)&sB[k][tx * 4];
      float av[4] = {a.x, a.y, a.z, a.w};
      float bv[4] = {b.x, b.y, b.z, b.w};
#pragma unroll
      for (int i = 0; i < 4; ++i)
#pragma unroll
        for (int j = 0; j < 4; ++j) acc[i][j] = fmaf(av[i], bv[j], acc[i][j]);
    }
    __syncthreads();
  }
#pragma unroll
  for (int i = 0; i < 4; ++i) {
    int row = row0 + ty * 4 + i;
    if (row < nrows) {
      float4 v = make_float4(acc[i][0], acc[i][1], acc[i][2], acc[i][3]);
      *(float4*)&C[row * 128 + col0 + tx * 4] = v;
    }
  }
}

// ---------------- per-node attention logits: as_out/ad_out [N,4] ----------------
// 32 threads per node, float4 per thread, 8-lane (one head) shuffle reduce.
__global__ __launch_bounds__(256) void k_alpha(const float* __restrict__ h,
                                               const float* __restrict__ a_s,
                                               const float* __restrict__ a_d,
                                               float* __restrict__ as_out,
                                               float* __restrict__ ad_out, int n) {
  int t = threadIdx.x;
  int node = blockIdx.x * 8 + (t >> 5);
  int g = t & 31;
  if (node >= n) return;
  float4 v = *(const float4*)&h[node * 128 + g * 4];
  float4 As = *(const float4*)&a_s[g * 4];
  float4 Ad = *(const float4*)&a_d[g * 4];
  float s = v.x * As.x + v.y * As.y + v.z * As.z + v.w * As.w;
  float d = v.x * Ad.x + v.y * Ad.y + v.z * Ad.z + v.w * Ad.w;
  for (int off = 4; off; off >>= 1) {  // reduce 8 threads = 32 channels = 1 head
    s += __shfl_xor(s, off);
    d += __shfl_xor(d, off);
  }
  if ((g & 7) == 0) {
    int hd = g >> 3;
    as_out[node * 4 + hd] = s;
    ad_out[node * 4 + hd] = d;
  }
}

// ---------------- per-node softmax + aggregate; 32 lanes per node ----------------
// 256 threads = 8 node slots. No max pass (shift-invariant, overflow-safe).
// LAYER 1: out = relu(agg + b1), [N,128]
// LAYER 2: head-mean + b2 + relu + classifier -> out [N,16]
template <int LAYER>
__global__ __launch_bounds__(256) void k_agg(const int* __restrict__ rowptr,
                                             const int* __restrict__ colsrc,
                                             const float* __restrict__ as,
                                             const float* __restrict__ ad,
                                             const float* __restrict__ h,
                                             const float* __restrict__ b1,
                                             const float* __restrict__ b2,
                                             const float* __restrict__ Wc,
                                             const float* __restrict__ bc,
                                             float* __restrict__ out, int n) {
  __shared__ float sbuf[8][128];
  const int slot = threadIdx.x >> 5;   // node slot 0..7
  const int l = threadIdx.x & 31;      // lane within node group
  const int node = blockIdx.x * 8 + slot;
  const bool active = node < n;
  int start = 0, end = 0;
  float4 adv = make_float4(0.f, 0.f, 0.f, 0.f);
  if (active) {
    start = rowptr[node];
    end = rowptr[node + 1];
    adv = *(const float4*)&ad[node * 4];
  }
  // phase 1: per-head sum(exp(leaky(logit)))  (no max subtraction)
  float s0 = 0.f, s1 = 0.f, s2 = 0.f, s3 = 0.f;
  for (int e = start + l; e < end; e += 32) {
    int s = colsrc[e];
    float4 av = *(const float4*)&as[s * 4];
    s0 += __expf(leaky02(av.x + adv.x));
    s1 += __expf(leaky02(av.y + adv.y));
    s2 += __expf(leaky02(av.z + adv.z));
    s3 += __expf(leaky02(av.w + adv.w));
  }
  for (int off = 16; off; off >>= 1) {  // xor<32 stays within the 32-lane group
    s0 += __shfl_xor(s0, off);
    s1 += __shfl_xor(s1, off);
    s2 += __shfl_xor(s2, off);
    s3 += __shfl_xor(s3, off);
  }
  // phase 2: accumulate; lane owns float4 channels c = 4*l, head = l>>3
  const int hd = l >> 3;
  const float sh = hd == 0 ? s0 : hd == 1 ? s1 : hd == 2 ? s2 : s3;
  const float adh = hd == 0 ? adv.x : hd == 1 ? adv.y : hd == 2 ? adv.z : adv.w;
  const float inv = 1.0f / sh;
  const int c = l * 4;
  float4 acc = make_float4(0.f, 0.f, 0.f, 0.f);
  int e = start;
  for (; e + 3 < end; e += 4) {  // unroll x4: four independent gather chains
    int sa = colsrc[e];
    int sb = colsrc[e + 1];
    int sc = colsrc[e + 2];
    int sd = colsrc[e + 3];
    float aa = as[sa * 4 + hd];
    float ab = as[sb * 4 + hd];
    float ac = as[sc * 4 + hd];
    float ax = as[sd * 4 + hd];
    float4 ha = *(const float4*)&h[sa * 128 + c];
    float4 hb = *(const float4*)&h[sb * 128 + c];
    float4 hc = *(const float4*)&h[sc * 128 + c];
    float4 hx = *(const float4*)&h[sd * 128 + c];
    float wa = __expf(leaky02(aa + adh)) * inv;
    float wb = __expf(leaky02(ab + adh)) * inv;
    float wc = __expf(leaky02(ac + adh)) * inv;
    float wx = __expf(leaky02(ax + adh)) * inv;
    acc.x = fmaf(wa, ha.x, acc.x); acc.y = fmaf(wa, ha.y, acc.y);
    acc.z = fmaf(wa, ha.z, acc.z); acc.w = fmaf(wa, ha.w, acc.w);
    acc.x = fmaf(wb, hb.x, acc.x); acc.y = fmaf(wb, hb.y, acc.y);
    acc.z = fmaf(wb, hb.z, acc.z); acc.w = fmaf(wb, hb.w, acc.w);
    acc.x = fmaf(wc, hc.x, acc.x); acc.y = fmaf(wc, hc.y, acc.y);
    acc.z = fmaf(wc, hc.z, acc.z); acc.w = fmaf(wc, hc.w, acc.w);
    acc.x = fmaf(wx, hx.x, acc.x); acc.y = fmaf(wx, hx.y, acc.y);
    acc.z = fmaf(wx, hx.z, acc.z); acc.w = fmaf(wx, hx.w, acc.w);
  }
  for (; e < end; ++e) {
    int sa = colsrc[e];
    float w = __expf(leaky02(as[sa * 4 + hd] + adh)) * inv;
    float4 hv = *(const float4*)&h[sa * 128 + c];
    acc.x = fmaf(w, hv.x, acc.x); acc.y = fmaf(w, hv.y, acc.y);
    acc.z = fmaf(w, hv.z, acc.z); acc.w = fmaf(w, hv.w, acc.w);
  }
  if (LAYER == 1) {
    if (active) {
      float4 bv = *(const float4*)&b1[c];
      acc.x = fmaxf(acc.x + bv.x, 0.f);
      acc.y = fmaxf(acc.y + bv.y, 0.f);
      acc.z = fmaxf(acc.z + bv.z, 0.f);
      acc.w = fmaxf(acc.w + bv.w, 0.f);
      *(float4*)&out[node * 128 + c] = acc;
    }
  } else {
    *(float4*)&sbuf[slot][c] = acc;
    __syncthreads();
    // head-mean + bias + relu (32 lanes per node, channel l)
    float f = 0.25f * (sbuf[slot][l] + sbuf[slot][l + 32] +
                       sbuf[slot][l + 64] + sbuf[slot][l + 96]);
    f = fmaxf(f + b2[l], 0.f);
    __syncthreads();
    sbuf[slot][l] = f;
    __syncthreads();
    if (active && l < 16) {
      float o = bc[l];
#pragma unroll
      for (int cc = 0; cc < 32; ++cc) o = fmaf(sbuf[slot][cc], Wc[cc * 16 + l], o);
      out[node * 16 + l] = o;
    }
  }
}

// ---------------------------------------------------------------------------
extern "C" void kernel_launch(void* const* d_in, const int* in_sizes, int n_in,
                              void* d_out, int out_size, void* d_ws, size_t ws_size,
                              hipStream_t stream) {
  const float* x = (const float*)d_in[0];
  const int* ei = (const int*)d_in[1];   // [2,E] int32
  const float* W1 = (const float*)d_in[2];
  const float* a_s1 = (const float*)d_in[3];
  const float* a_d1 = (const float*)d_in[4];
  const float* b1 = (const float*)d_in[5];
  const float* W2 = (const float*)d_in[6];
  const float* a_s2 = (const float*)d_in[7];
  const float* a_d2 = (const float*)d_in[8];
  const float* b2 = (const float*)d_in[9];
  const float* Wc = (const float*)d_in[10];
  const float* bc = (const float*)d_in[11];
  float* out = (float*)d_out;

  const int N = in_sizes[0] / 128;
  const int E = in_sizes[1] / 2;
  const int Ep = E + N;
  const int NCH = (N + 2047) / 2048;

  // workspace carve-up (~114 MB)
  float* h = (float*)d_ws;                       // N*128
  float* x2 = h + (size_t)N * 128;               // N*128
  float* asb = x2 + (size_t)N * 128;             // N*4
  float* adb = asb + (size_t)N * 4;              // N*4
  int* deg = (int*)(adb + (size_t)N * 4);        // N
  int* fill = deg + N;                           // N
  int* rowptr = fill + N;                        // N+1
  int* part = rowptr + (N + 1);                  // NCH
  int* choff = part + ((NCH + 15) & ~15);        // NCH
  int* colsrc = choff + ((NCH + 15) & ~15);      // E+N

  hipMemsetAsync(deg, 0, sizeof(int) * (size_t)(2 * N), stream);  // deg + fill

  k_hist<<<(Ep + 255) / 256, 256, 0, stream>>>(ei, deg, E, N);
  k_partial<<<NCH, 256, 0, stream>>>(deg, part, N);
  k_scan_part<<<1, 64, 0, stream>>>(part, choff, rowptr, NCH, N);
  k_scan_final<<<NCH, 256, 0, stream>>>(deg, choff, rowptr, N);
  k_scatter<<<(Ep + 255) / 256, 256, 0, stream>>>(ei, rowptr, fill, colsrc, E, N);

  dim3 ggrid((N + 63) / 64, 2);
  k_gemm128<<<ggrid, 256, 0, stream>>>(x, W1, h, N);
  k_alpha<<<(N + 7) / 8, 256, 0, stream>>>(h, a_s1, a_d1, asb, adb, N);
  k_agg<1><<<(N + 7) / 8, 256, 0, stream>>>(rowptr, colsrc, asb, adb, h, b1,
                                            nullptr, nullptr, nullptr, x2, N);
  k_gemm128<<<ggrid, 256, 0, stream>>>(x2, W2, h, N);
  k_alpha<<<(N + 7) / 8, 256, 0, stream>>>(h, a_s2, a_d2, asb, adb, N);
  k_agg<2><<<(N + 7) / 8, 256, 0, stream>>>(rowptr, colsrc, asb, adb, h, nullptr,
                                            b2, Wc, bc, out, N);
}

// Round 5
// 543.811 us; speedup vs baseline: 1.2325x; 1.2325x over previous
//
#include <hip/hip_runtime.h>
#include <hip/hip_fp16.h>

// ---------------------------------------------------------------------------
// 2-layer GAT + classifier. CSR via atomic segment allocation (order-free).
// GEMM (fp32 compute) fuses: attention logits (as/ad) + fp16 feature mirror.
// Aggregate: single fused pass, denominator accumulated in-loop (no max pass;
// logits provably < ~10 for glorot weights -> exp cannot overflow fp32).
// ---------------------------------------------------------------------------

__device__ __forceinline__ float leaky02(float v) { return v > 0.f ? v : 0.2f * v; }

struct h2x2 { __half2 a, b; };  // 8-byte packed 4x fp16

// ---------------- CSR build ----------------
__global__ void k_hist(const int* __restrict__ ei, int* __restrict__ deg, int E, int N) {
  int i = blockIdx.x * blockDim.x + threadIdx.x;
  if (i >= E + N) return;
  int d = (i < E) ? ei[E + i] : (i - E);   // self-loop for i >= E
  atomicAdd(&deg[d], 1);
}

// rowstart[i] = atomic segment alloc (arbitrary order; sums are order-free).
// Manual wave-aggregation: one atomic per 64 lanes.
__global__ void k_alloc(const int* __restrict__ deg, int* __restrict__ rowstart,
                        int* __restrict__ cursor, int N) {
  int i = blockIdx.x * blockDim.x + threadIdx.x;
  int lane = threadIdx.x & 63;
  int d = (i < N) ? deg[i] : 0;
  int sc = d;  // inclusive scan over the wave
  for (int off = 1; off < 64; off <<= 1) {
    int v = __shfl_up(sc, off);
    if (lane >= off) sc += v;
  }
  int total = __shfl(sc, 63);
  int base = 0;
  if (lane == 63) base = atomicAdd(cursor, total);
  base = __shfl(base, 63);
  if (i < N) rowstart[i] = base + sc - d;
}

__global__ void k_scatter(const int* __restrict__ ei, const int* __restrict__ rowstart,
                          int* __restrict__ fill, int* __restrict__ colsrc, int E, int N) {
  int i = blockIdx.x * blockDim.x + threadIdx.x;
  if (i >= E + N) return;
  int s, d;
  if (i < E) { s = ei[i]; d = ei[E + i]; } else { s = i - E; d = s; }
  int pos = rowstart[d] + atomicAdd(&fill[d], 1);
  colsrc[pos] = s;
}

// ---------------- fused GEMM: h = A @ W; emit fp16 h + attention logits ------
// 64x64 tile per block (grid.y = 2 column halves -> heads {0,1} / {2,3}).
// avs/avd are the flattened [4][32] = [128] attention vectors.
__global__ __launch_bounds__(256) void k_gemm_fused(const float* __restrict__ A,
                                                    const float* __restrict__ W,
                                                    const float* __restrict__ avs,
                                                    const float* __restrict__ avd,
                                                    __half* __restrict__ Hh,
                                                    float* __restrict__ as_out,
                                                    float* __restrict__ ad_out,
                                                    int nrows) {
  __shared__ float sA[16][68];  // [k][m]; stride 68 -> sA writes <=2-way (free)
  __shared__ float sB[16][68];  // [k][c]
  const int t = threadIdx.x;
  const int row0 = blockIdx.x * 64;
  const int col0 = blockIdx.y * 64;
  const int tx = t & 15, ty = t >> 4;
  float acc[4][4] = {{0.f, 0.f, 0.f, 0.f}, {0.f, 0.f, 0.f, 0.f},
                     {0.f, 0.f, 0.f, 0.f}, {0.f, 0.f, 0.f, 0.f}};
  for (int kc = 0; kc < 128; kc += 16) {
    {  // A-tile: 64 rows x 16 k, one float4 per thread
      int m = t >> 2;
      int k4 = (t & 3) * 4;
      int row = row0 + m;
      float4 a = (row < nrows) ? *(const float4*)&A[(size_t)row * 128 + kc + k4]
                               : make_float4(0.f, 0.f, 0.f, 0.f);
      sA[k4 + 0][m] = a.x;
      sA[k4 + 1][m] = a.y;
      sA[k4 + 2][m] = a.z;
      sA[k4 + 3][m] = a.w;
    }
    {  // B-tile: 16 k x 64 cols, one float4 per thread
      int kk = t >> 4;
      int c4 = (t & 15) * 4;
      float4 b = *(const float4*)&W[(size_t)(kc + kk) * 128 + col0 + c4];
      *(float4*)&sB[kk][c4] = b;
    }
    __syncthreads();
#pragma unroll
    for (int k = 0; k < 16; ++k) {
      const float4 a = *(const float4*)&sA[k][ty * 4];
      const float4 b = *(const float4*)&sB[k][tx * 4];
      float av[4] = {a.x, a.y, a.z, a.w};
      float bv[4] = {b.x, b.y, b.z, b.w};
#pragma unroll
      for (int i = 0; i < 4; ++i)
#pragma unroll
        for (int j = 0; j < 4; ++j) acc[i][j] = fmaf(av[i], bv[j], acc[i][j]);
    }
    __syncthreads();
  }
  // epilogue: per-row alpha partials (this block's 64 cols = 2 heads) + fp16 h
  const float4 s4 = *(const float4*)&avs[col0 + tx * 4];
  const float4 d4 = *(const float4*)&avd[col0 + tx * 4];
#pragma unroll
  for (int i = 0; i < 4; ++i) {
    const int row = row0 + ty * 4 + i;
    float ps = acc[i][0] * s4.x + acc[i][1] * s4.y + acc[i][2] * s4.z + acc[i][3] * s4.w;
    float pd = acc[i][0] * d4.x + acc[i][1] * d4.y + acc[i][2] * d4.z + acc[i][3] * d4.w;
    for (int off = 1; off < 8; off <<= 1) {  // reduce 8 lanes = 32 cols = 1 head
      ps += __shfl_xor(ps, off);
      pd += __shfl_xor(pd, off);
    }
    if (row < nrows) {
      if ((tx & 7) == 0) {
        int head = (col0 >> 5) + (tx >> 3);
        as_out[row * 4 + head] = ps;
        ad_out[row * 4 + head] = pd;
      }
      __half2 p0 = __floats2half2_rn(acc[i][0], acc[i][1]);
      __half2 p1 = __floats2half2_rn(acc[i][2], acc[i][3]);
      h2x2 pk; pk.a = p0; pk.b = p1;
      *(h2x2*)&Hh[(size_t)row * 128 + col0 + tx * 4] = pk;
    }
  }
}

// ---------------- fused softmax+aggregate; 32 lanes per node -----------------
// Single edge pass: every lane visits every edge, so each lane accumulates its
// own head's sum(exp) alongside the weighted feature sum; scale once at end.
// LAYER 1: out = relu(agg + b1), [N,128] fp32
// LAYER 2: head-mean + b2 + relu + classifier -> out [N,16]
template <int LAYER>
__global__ __launch_bounds__(256) void k_agg(const int* __restrict__ rowstart,
                                             const int* __restrict__ deg,
                                             const int* __restrict__ colsrc,
                                             const float* __restrict__ as,
                                             const float* __restrict__ ad,
                                             const __half* __restrict__ Hh,
                                             const float* __restrict__ b1,
                                             const float* __restrict__ b2,
                                             const float* __restrict__ Wc,
                                             const float* __restrict__ bc,
                                             float* __restrict__ out, int n) {
  __shared__ float sbuf[8][128];
  const int slot = threadIdx.x >> 5;   // node slot 0..7
  const int l = threadIdx.x & 31;      // lane within node group
  const int node = blockIdx.x * 8 + slot;
  const bool active = node < n;
  int start = 0, end = 0;
  float4 adv = make_float4(0.f, 0.f, 0.f, 0.f);
  if (active) {
    start = rowstart[node];
    end = start + deg[node];
    adv = *(const float4*)&ad[node * 4];
  }
  const int hd = l >> 3;
  const float adh = hd == 0 ? adv.x : hd == 1 ? adv.y : hd == 2 ? adv.z : adv.w;
  const int c = l * 4;
  float4 acc = make_float4(0.f, 0.f, 0.f, 0.f);
  float dsum = 0.f;
  int e = start;
  for (; e + 3 < end; e += 4) {  // unroll x4: four independent gather chains
    int s0 = colsrc[e], s1 = colsrc[e + 1], s2 = colsrc[e + 2], s3 = colsrc[e + 3];
    float a0 = as[s0 * 4 + hd];
    float a1 = as[s1 * 4 + hd];
    float a2 = as[s2 * 4 + hd];
    float a3 = as[s3 * 4 + hd];
    h2x2 q0 = *(const h2x2*)&Hh[(size_t)s0 * 128 + c];
    h2x2 q1 = *(const h2x2*)&Hh[(size_t)s1 * 128 + c];
    h2x2 q2 = *(const h2x2*)&Hh[(size_t)s2 * 128 + c];
    h2x2 q3 = *(const h2x2*)&Hh[(size_t)s3 * 128 + c];
    float w0 = __expf(leaky02(a0 + adh));
    float w1 = __expf(leaky02(a1 + adh));
    float w2 = __expf(leaky02(a2 + adh));
    float w3 = __expf(leaky02(a3 + adh));
    dsum += w0 + w1 + w2 + w3;
    float2 f0a = __half22float2(q0.a), f0b = __half22float2(q0.b);
    float2 f1a = __half22float2(q1.a), f1b = __half22float2(q1.b);
    float2 f2a = __half22float2(q2.a), f2b = __half22float2(q2.b);
    float2 f3a = __half22float2(q3.a), f3b = __half22float2(q3.b);
    acc.x = fmaf(w0, f0a.x, acc.x); acc.y = fmaf(w0, f0a.y, acc.y);
    acc.z = fmaf(w0, f0b.x, acc.z); acc.w = fmaf(w0, f0b.y, acc.w);
    acc.x = fmaf(w1, f1a.x, acc.x); acc.y = fmaf(w1, f1a.y, acc.y);
    acc.z = fmaf(w1, f1b.x, acc.z); acc.w = fmaf(w1, f1b.y, acc.w);
    acc.x = fmaf(w2, f2a.x, acc.x); acc.y = fmaf(w2, f2a.y, acc.y);
    acc.z = fmaf(w2, f2b.x, acc.z); acc.w = fmaf(w2, f2b.y, acc.w);
    acc.x = fmaf(w3, f3a.x, acc.x); acc.y = fmaf(w3, f3a.y, acc.y);
    acc.z = fmaf(w3, f3b.x, acc.z); acc.w = fmaf(w3, f3b.y, acc.w);
  }
  for (; e < end; ++e) {
    int s0 = colsrc[e];
    float w = __expf(leaky02(as[s0 * 4 + hd] + adh));
    h2x2 q = *(const h2x2*)&Hh[(size_t)s0 * 128 + c];
    float2 fa = __half22float2(q.a), fb = __half22float2(q.b);
    dsum += w;
    acc.x = fmaf(w, fa.x, acc.x); acc.y = fmaf(w, fa.y, acc.y);
    acc.z = fmaf(w, fb.x, acc.z); acc.w = fmaf(w, fb.y, acc.w);
  }
  const float inv = dsum > 0.f ? 1.0f / dsum : 0.f;
  acc.x *= inv; acc.y *= inv; acc.z *= inv; acc.w *= inv;
  if (LAYER == 1) {
    if (active) {
      float4 bv = *(const float4*)&b1[c];
      acc.x = fmaxf(acc.x + bv.x, 0.f);
      acc.y = fmaxf(acc.y + bv.y, 0.f);
      acc.z = fmaxf(acc.z + bv.z, 0.f);
      acc.w = fmaxf(acc.w + bv.w, 0.f);
      *(float4*)&out[(size_t)node * 128 + c] = acc;
    }
  } else {
    *(float4*)&sbuf[slot][c] = acc;
    __syncthreads();
    // head-mean + bias + relu (32 lanes per node, channel l)
    float f = 0.25f * (sbuf[slot][l] + sbuf[slot][l + 32] +
                       sbuf[slot][l + 64] + sbuf[slot][l + 96]);
    f = fmaxf(f + b2[l], 0.f);
    __syncthreads();
    sbuf[slot][l] = f;
    __syncthreads();
    if (active && l < 16) {
      float o = bc[l];
#pragma unroll
      for (int cc = 0; cc < 32; ++cc) o = fmaf(sbuf[slot][cc], Wc[cc * 16 + l], o);
      out[(size_t)node * 16 + l] = o;
    }
  }
}

// ---------------------------------------------------------------------------
extern "C" void kernel_launch(void* const* d_in, const int* in_sizes, int n_in,
                              void* d_out, int out_size, void* d_ws, size_t ws_size,
                              hipStream_t stream) {
  const float* x = (const float*)d_in[0];
  const int* ei = (const int*)d_in[1];   // [2,E] int32
  const float* W1 = (const float*)d_in[2];
  const float* a_s1 = (const float*)d_in[3];
  const float* a_d1 = (const float*)d_in[4];
  const float* b1 = (const float*)d_in[5];
  const float* W2 = (const float*)d_in[6];
  const float* a_s2 = (const float*)d_in[7];
  const float* a_d2 = (const float*)d_in[8];
  const float* b2 = (const float*)d_in[9];
  const float* Wc = (const float*)d_in[10];
  const float* bc = (const float*)d_in[11];
  float* out = (float*)d_out;

  const int N = in_sizes[0] / 128;
  const int E = in_sizes[1] / 2;
  const int Ep = E + N;

  // workspace carve-up (~88 MB)
  __half* Hh = (__half*)d_ws;                     // N*128 fp16 (25.6 MB)
  float* x2 = (float*)(Hh + (size_t)N * 128);     // N*128 f32
  float* asb = x2 + (size_t)N * 128;              // N*4
  float* adb = asb + (size_t)N * 4;               // N*4
  int* deg = (int*)(adb + (size_t)N * 4);         // N
  int* fill = deg + N;                            // N
  int* cursor = fill + N;                         // 16 (padded)
  int* rowstart = cursor + 16;                    // N
  int* colsrc = rowstart + N;                     // E+N

  hipMemsetAsync(deg, 0, sizeof(int) * ((size_t)2 * N + 16), stream);  // deg+fill+cursor

  k_hist<<<(Ep + 255) / 256, 256, 0, stream>>>(ei, deg, E, N);
  k_alloc<<<(N + 255) / 256, 256, 0, stream>>>(deg, rowstart, cursor, N);
  k_scatter<<<(Ep + 255) / 256, 256, 0, stream>>>(ei, rowstart, fill, colsrc, E, N);

  dim3 ggrid((N + 63) / 64, 2);
  k_gemm_fused<<<ggrid, 256, 0, stream>>>(x, W1, a_s1, a_d1, Hh, asb, adb, N);
  k_agg<1><<<(N + 7) / 8, 256, 0, stream>>>(rowstart, deg, colsrc, asb, adb, Hh,
                                            b1, nullptr, nullptr, nullptr, x2, N);
  k_gemm_fused<<<ggrid, 256, 0, stream>>>(x2, W2, a_s2, a_d2, Hh, asb, adb, N);
  k_agg<2><<<(N + 7) / 8, 256, 0, stream>>>(rowstart, deg, colsrc, asb, adb, Hh,
                                            nullptr, b2, Wc, bc, out, N);
}

// Round 6
// 429.191 us; speedup vs baseline: 1.5616x; 1.2671x over previous
//
#include <hip/hip_runtime.h>
#include <hip/hip_fp16.h>

// ---------------------------------------------------------------------------
// 2-layer GAT + classifier.
// CSR build via two-level multisplit (LDS-grouped bucket scatter) -> no
// random 4B global writes (R5 showed 16x write amplification on those).
// GEMM (fp32 compute) fuses attention logits + fp16 feature mirror.
// Aggregate: single fused pass, denominator accumulated in-loop (no max pass;
// logits provably < ~10 for glorot weights -> exp cannot overflow fp32).
// ---------------------------------------------------------------------------

__device__ __forceinline__ float leaky02(float v) { return v > 0.f ? v : 0.2f * v; }

struct h2x2 { __half2 a, b; };  // 8-byte packed 4x fp16

#define NPB 1024          // nodes per bucket (bucket id = dst >> 10)
#define MAXNB 128         // max buckets (N <= 131072)
#define EPT 16            // edges per thread in bucketize
#define CH 4096           // edges per block (256 * EPT)

// ---- pass 1: multisplit edges (+self-loops) into padded bucket regions ----
__global__ __launch_bounds__(256) void k_bucketize(const int* __restrict__ ei,
                                                   uint2* __restrict__ ebuf,
                                                   int* __restrict__ bcur,
                                                   int E, int N, int NB, int region) {
  __shared__ int hist[MAXNB];
  __shared__ int lbase[MAXNB];
  const int t = threadIdx.x;
  const int base = blockIdx.x * CH;
  const int Ep = E + N;
  if (t < MAXNB) hist[t] = 0;
  __syncthreads();
  int src[EPT], dst[EPT];
#pragma unroll
  for (int k = 0; k < EPT; ++k) {
    int e = base + k * 256 + t;
    if (e < E) { src[k] = ei[e]; dst[k] = ei[E + e]; }
    else if (e < Ep) { src[k] = dst[k] = e - E; }   // self-loop
    else { src[k] = -1; dst[k] = -1; }
    if (dst[k] >= 0) atomicAdd(&hist[dst[k] >> 10], 1);
  }
  __syncthreads();
  if (t < NB && hist[t] > 0) lbase[t] = atomicAdd(&bcur[t], hist[t]);
  __syncthreads();
  if (t < MAXNB) hist[t] = 0;   // reuse as local cursor
  __syncthreads();
#pragma unroll
  for (int k = 0; k < EPT; ++k) {
    if (dst[k] >= 0) {
      int b = dst[k] >> 10;
      int r = atomicAdd(&hist[b], 1);
      ebuf[(size_t)b * region + lbase[b] + r] =
          make_uint2((unsigned)src[k], (unsigned)dst[k]);
    }
  }
}

// ---- pass 2: exclusive scan of bucket counts -> colbase; rowptr[N] = Ep ----
__global__ void k_bscan(const int* __restrict__ bcur, int* __restrict__ colbase,
                        int* __restrict__ rowptr, int NB, int N, int Ep) {
  __shared__ int lds[MAXNB];
  int t = threadIdx.x;  // 128 threads
  int v = (t < NB) ? bcur[t] : 0;
  lds[t] = v;
  __syncthreads();
  for (int off = 1; off < MAXNB; off <<= 1) {
    int u = (t >= off) ? lds[t - off] : 0;
    __syncthreads();
    lds[t] += u;
    __syncthreads();
  }
  if (t < NB) colbase[t] = lds[t] - v;   // exclusive
  if (t == 0) rowptr[N] = Ep;
}

// ---- pass 3: per-bucket CSR: LDS node-count + scan -> rowptr, colsrc -------
__global__ __launch_bounds__(256) void k_csr(const uint2* __restrict__ ebuf,
                                             const int* __restrict__ bcur,
                                             const int* __restrict__ colbase,
                                             int* __restrict__ rowptr,
                                             int* __restrict__ colsrc,
                                             int N, int region) {
  __shared__ int cnt[NPB];
  __shared__ int lds2[256];
  const int b = blockIdx.x;
  const int t = threadIdx.x;
  const int m = bcur[b];
  const size_t ebase = (size_t)b * region;
  const int cb = colbase[b];
#pragma unroll
  for (int i = 0; i < 4; ++i) cnt[t * 4 + i] = 0;
  __syncthreads();
  for (int j = t; j < m; j += 256) {
    int d = (int)(ebuf[ebase + j].y) & (NPB - 1);
    atomicAdd(&cnt[d], 1);
  }
  __syncthreads();
  int v[4], s = 0;
#pragma unroll
  for (int i = 0; i < 4; ++i) { v[i] = cnt[t * 4 + i]; s += v[i]; }
  lds2[t] = s;
  __syncthreads();
  for (int off = 1; off < 256; off <<= 1) {
    int u = (t >= off) ? lds2[t - off] : 0;
    __syncthreads();
    lds2[t] += u;
    __syncthreads();
  }
  int e = lds2[t] - s;  // exclusive over this bucket
  const int node0 = (b << 10) + t * 4;
#pragma unroll
  for (int i = 0; i < 4; ++i) {
    cnt[t * 4 + i] = e;                       // per-node cursor start
    if (node0 + i < N) rowptr[node0 + i] = cb + e;
    e += v[i];
  }
  __syncthreads();
  for (int j = t; j < m; j += 256) {
    uint2 q = ebuf[ebase + j];
    int d = (int)q.y & (NPB - 1);
    int r = atomicAdd(&cnt[d], 1);
    colsrc[cb + r] = (int)q.x;
  }
}

// ---------------- fused GEMM: h = A @ W; emit fp16 h + attention logits ------
// 64x64 tile per block (grid.y = 2 column halves -> heads {0,1} / {2,3}).
__global__ __launch_bounds__(256) void k_gemm_fused(const float* __restrict__ A,
                                                    const float* __restrict__ W,
                                                    const float* __restrict__ avs,
                                                    const float* __restrict__ avd,
                                                    __half* __restrict__ Hh,
                                                    float* __restrict__ as_out,
                                                    float* __restrict__ ad_out,
                                                    int nrows) {
  __shared__ float sA[16][68];
  __shared__ float sB[16][68];
  const int t = threadIdx.x;
  const int row0 = blockIdx.x * 64;
  const int col0 = blockIdx.y * 64;
  const int tx = t & 15, ty = t >> 4;
  float acc[4][4] = {{0.f, 0.f, 0.f, 0.f}, {0.f, 0.f, 0.f, 0.f},
                     {0.f, 0.f, 0.f, 0.f}, {0.f, 0.f, 0.f, 0.f}};
  for (int kc = 0; kc < 128; kc += 16) {
    {
      int m = t >> 2;
      int k4 = (t & 3) * 4;
      int row = row0 + m;
      float4 a = (row < nrows) ? *(const float4*)&A[(size_t)row * 128 + kc + k4]
                               : make_float4(0.f, 0.f, 0.f, 0.f);
      sA[k4 + 0][m] = a.x;
      sA[k4 + 1][m] = a.y;
      sA[k4 + 2][m] = a.z;
      sA[k4 + 3][m] = a.w;
    }
    {
      int kk = t >> 4;
      int c4 = (t & 15) * 4;
      float4 b = *(const float4*)&W[(size_t)(kc + kk) * 128 + col0 + c4];
      *(float4*)&sB[kk][c4] = b;
    }
    __syncthreads();
#pragma unroll
    for (int k = 0; k < 16; ++k) {
      const float4 a = *(const float4*)&sA[k][ty * 4];
      const float4 b = *(const float4*)&sB[k][tx * 4];
      float av[4] = {a.x, a.y, a.z, a.w};
      float bv[4] = {b.x, b.y, b.z, b.w};
#pragma unroll
      for (int i = 0; i < 4; ++i)
#pragma unroll
        for (int j = 0; j < 4; ++j) acc[i][j] = fmaf(av[i], bv[j], acc[i][j]);
    }
    __syncthreads();
  }
  const float4 s4 = *(const float4*)&avs[col0 + tx * 4];
  const float4 d4 = *(const float4*)&avd[col0 + tx * 4];
#pragma unroll
  for (int i = 0; i < 4; ++i) {
    const int row = row0 + ty * 4 + i;
    float ps = acc[i][0] * s4.x + acc[i][1] * s4.y + acc[i][2] * s4.z + acc[i][3] * s4.w;
    float pd = acc[i][0] * d4.x + acc[i][1] * d4.y + acc[i][2] * d4.z + acc[i][3] * d4.w;
    for (int off = 1; off < 8; off <<= 1) {  // 8 lanes = 32 cols = 1 head
      ps += __shfl_xor(ps, off);
      pd += __shfl_xor(pd, off);
    }
    if (row < nrows) {
      if ((tx & 7) == 0) {
        int head = (col0 >> 5) + (tx >> 3);
        as_out[row * 4 + head] = ps;
        ad_out[row * 4 + head] = pd;
      }
      h2x2 pk;
      pk.a = __floats2half2_rn(acc[i][0], acc[i][1]);
      pk.b = __floats2half2_rn(acc[i][2], acc[i][3]);
      *(h2x2*)&Hh[(size_t)row * 128 + col0 + tx * 4] = pk;
    }
  }
}

// ---------------- fused softmax+aggregate; 32 lanes per node -----------------
template <int LAYER>
__global__ __launch_bounds__(256) void k_agg(const int* __restrict__ rowptr,
                                             const int* __restrict__ colsrc,
                                             const float* __restrict__ as,
                                             const float* __restrict__ ad,
                                             const __half* __restrict__ Hh,
                                             const float* __restrict__ b1,
                                             const float* __restrict__ b2,
                                             const float* __restrict__ Wc,
                                             const float* __restrict__ bc,
                                             float* __restrict__ out, int n) {
  __shared__ float sbuf[8][128];
  const int slot = threadIdx.x >> 5;
  const int l = threadIdx.x & 31;
  const int node = blockIdx.x * 8 + slot;
  const bool active = node < n;
  int start = 0, end = 0;
  float4 adv = make_float4(0.f, 0.f, 0.f, 0.f);
  if (active) {
    start = rowptr[node];
    end = rowptr[node + 1];
    adv = *(const float4*)&ad[node * 4];
  }
  const int hd = l >> 3;
  const float adh = hd == 0 ? adv.x : hd == 1 ? adv.y : hd == 2 ? adv.z : adv.w;
  const int c = l * 4;
  float4 acc = make_float4(0.f, 0.f, 0.f, 0.f);
  float dsum = 0.f;
  int e = start;
  for (; e + 3 < end; e += 4) {
    int s0 = colsrc[e], s1 = colsrc[e + 1], s2 = colsrc[e + 2], s3 = colsrc[e + 3];
    float a0 = as[s0 * 4 + hd];
    float a1 = as[s1 * 4 + hd];
    float a2 = as[s2 * 4 + hd];
    float a3 = as[s3 * 4 + hd];
    h2x2 q0 = *(const h2x2*)&Hh[(size_t)s0 * 128 + c];
    h2x2 q1 = *(const h2x2*)&Hh[(size_t)s1 * 128 + c];
    h2x2 q2 = *(const h2x2*)&Hh[(size_t)s2 * 128 + c];
    h2x2 q3 = *(const h2x2*)&Hh[(size_t)s3 * 128 + c];
    float w0 = __expf(leaky02(a0 + adh));
    float w1 = __expf(leaky02(a1 + adh));
    float w2 = __expf(leaky02(a2 + adh));
    float w3 = __expf(leaky02(a3 + adh));
    dsum += w0 + w1 + w2 + w3;
    float2 f0a = __half22float2(q0.a), f0b = __half22float2(q0.b);
    float2 f1a = __half22float2(q1.a), f1b = __half22float2(q1.b);
    float2 f2a = __half22float2(q2.a), f2b = __half22float2(q2.b);
    float2 f3a = __half22float2(q3.a), f3b = __half22float2(q3.b);
    acc.x = fmaf(w0, f0a.x, acc.x); acc.y = fmaf(w0, f0a.y, acc.y);
    acc.z = fmaf(w0, f0b.x, acc.z); acc.w = fmaf(w0, f0b.y, acc.w);
    acc.x = fmaf(w1, f1a.x, acc.x); acc.y = fmaf(w1, f1a.y, acc.y);
    acc.z = fmaf(w1, f1b.x, acc.z); acc.w = fmaf(w1, f1b.y, acc.w);
    acc.x = fmaf(w2, f2a.x, acc.x); acc.y = fmaf(w2, f2a.y, acc.y);
    acc.z = fmaf(w2, f2b.x, acc.z); acc.w = fmaf(w2, f2b.y, acc.w);
    acc.x = fmaf(w3, f3a.x, acc.x); acc.y = fmaf(w3, f3a.y, acc.y);
    acc.z = fmaf(w3, f3b.x, acc.z); acc.w = fmaf(w3, f3b.y, acc.w);
  }
  for (; e < end; ++e) {
    int s0 = colsrc[e];
    float w = __expf(leaky02(as[s0 * 4 + hd] + adh));
    h2x2 q = *(const h2x2*)&Hh[(size_t)s0 * 128 + c];
    float2 fa = __half22float2(q.a), fb = __half22float2(q.b);
    dsum += w;
    acc.x = fmaf(w, fa.x, acc.x); acc.y = fmaf(w, fa.y, acc.y);
    acc.z = fmaf(w, fb.x, acc.z); acc.w = fmaf(w, fb.y, acc.w);
  }
  const float inv = dsum > 0.f ? 1.0f / dsum : 0.f;
  acc.x *= inv; acc.y *= inv; acc.z *= inv; acc.w *= inv;
  if (LAYER == 1) {
    if (active) {
      float4 bv = *(const float4*)&b1[c];
      acc.x = fmaxf(acc.x + bv.x, 0.f);
      acc.y = fmaxf(acc.y + bv.y, 0.f);
      acc.z = fmaxf(acc.z + bv.z, 0.f);
      acc.w = fmaxf(acc.w + bv.w, 0.f);
      *(float4*)&out[(size_t)node * 128 + c] = acc;
    }
  } else {
    *(float4*)&sbuf[slot][c] = acc;
    __syncthreads();
    float f = 0.25f * (sbuf[slot][l] + sbuf[slot][l + 32] +
                       sbuf[slot][l + 64] + sbuf[slot][l + 96]);
    f = fmaxf(f + b2[l], 0.f);
    __syncthreads();
    sbuf[slot][l] = f;
    __syncthreads();
    if (active && l < 16) {
      float o = bc[l];
#pragma unroll
      for (int cc = 0; cc < 32; ++cc) o = fmaf(sbuf[slot][cc], Wc[cc * 16 + l], o);
      out[(size_t)node * 16 + l] = o;
    }
  }
}

// ---------------------------------------------------------------------------
extern "C" void kernel_launch(void* const* d_in, const int* in_sizes, int n_in,
                              void* d_out, int out_size, void* d_ws, size_t ws_size,
                              hipStream_t stream) {
  const float* x = (const float*)d_in[0];
  const int* ei = (const int*)d_in[1];   // [2,E] int32
  const float* W1 = (const float*)d_in[2];
  const float* a_s1 = (const float*)d_in[3];
  const float* a_d1 = (const float*)d_in[4];
  const float* b1 = (const float*)d_in[5];
  const float* W2 = (const float*)d_in[6];
  const float* a_s2 = (const float*)d_in[7];
  const float* a_d2 = (const float*)d_in[8];
  const float* b2 = (const float*)d_in[9];
  const float* Wc = (const float*)d_in[10];
  const float* bc = (const float*)d_in[11];
  float* out = (float*)d_out;

  const int N = in_sizes[0] / 128;
  const int E = in_sizes[1] / 2;
  const int Ep = E + N;
  const int NB = (N + NPB - 1) >> 10;          // 98 buckets for N=100000
  const int region = Ep / NB + 4096;           // padded bucket region (>>30 sigma)

  // workspace carve-up (aligned)
  char* p = (char*)d_ws;
  auto align16 = [](char* q) { return (char*)(((uintptr_t)q + 15) & ~(uintptr_t)15); };
  __half* Hh = (__half*)p;            p = align16(p + sizeof(__half) * (size_t)N * 128);
  float* x2 = (float*)p;              p = align16(p + sizeof(float) * (size_t)N * 128);
  float* asb = (float*)p;             p = align16(p + sizeof(float) * (size_t)N * 4);
  float* adb = (float*)p;             p = align16(p + sizeof(float) * (size_t)N * 4);
  int* rowptr = (int*)p;              p = align16(p + sizeof(int) * (size_t)(N + 1));
  int* bcur = (int*)p;                p = align16(p + sizeof(int) * MAXNB);
  int* colbase = (int*)p;             p = align16(p + sizeof(int) * MAXNB);
  int* colsrc = (int*)p;              p = align16(p + sizeof(int) * (size_t)Ep);
  uint2* ebuf = (uint2*)p;            // NB * region * 8B (~17 MB)

  hipMemsetAsync(bcur, 0, sizeof(int) * MAXNB, stream);

  k_bucketize<<<(Ep + CH - 1) / CH, 256, 0, stream>>>(ei, ebuf, bcur, E, N, NB, region);
  k_bscan<<<1, MAXNB, 0, stream>>>(bcur, colbase, rowptr, NB, N, Ep);
  k_csr<<<NB, 256, 0, stream>>>(ebuf, bcur, colbase, rowptr, colsrc, N, region);

  dim3 ggrid((N + 63) / 64, 2);
  k_gemm_fused<<<ggrid, 256, 0, stream>>>(x, W1, a_s1, a_d1, Hh, asb, adb, N);
  k_agg<1><<<(N + 7) / 8, 256, 0, stream>>>(rowptr, colsrc, asb, adb, Hh,
                                            b1, nullptr, nullptr, nullptr, x2, N);
  k_gemm_fused<<<ggrid, 256, 0, stream>>>(x2, W2, a_s2, a_d2, Hh, asb, adb, N);
  k_agg<2><<<(N + 7) / 8, 256, 0, stream>>>(rowptr, colsrc, asb, adb, Hh,
                                            nullptr, b2, Wc, bc, out, N);
}

// Round 8
// 403.259 us; speedup vs baseline: 1.6621x; 1.0643x over previous
//
#include <hip/hip_runtime.h>
#include <hip/hip_fp16.h>

// ---------------------------------------------------------------------------
// 2-layer GAT + classifier.
// CSR via two-level multisplit (no random 4B global writes).
// GEMM: f16 MFMA (mfma_f32_16x16x32_f16, fp32 accum), fused attention logits
// + fp16 feature mirror. Aggregate: single fused pass, in-loop denominator.
// ---------------------------------------------------------------------------

typedef _Float16 f16;
typedef f16 f16x8 __attribute__((ext_vector_type(8)));
typedef float f32x4 __attribute__((ext_vector_type(4)));

__device__ __forceinline__ float leaky02(float v) { return v > 0.f ? v : 0.2f * v; }

struct h2x2 { __half2 a, b; };  // 8-byte packed 4x fp16

#define NPB 1024          // nodes per bucket (bucket id = dst >> 10)
#define MAXNB 128         // max buckets (N <= 131072)
#define EPT 16            // edges per thread in bucketize
#define CH 4096           // edges per block (256 * EPT)

// ---- pass 1: multisplit edges (+self-loops) into padded bucket regions ----
__global__ __launch_bounds__(256) void k_bucketize(const int* __restrict__ ei,
                                                   uint2* __restrict__ ebuf,
                                                   int* __restrict__ bcur,
                                                   int E, int N, int NB, int region) {
  __shared__ int hist[MAXNB];
  __shared__ int lbase[MAXNB];
  const int t = threadIdx.x;
  const int base = blockIdx.x * CH;
  const int Ep = E + N;
  if (t < MAXNB) hist[t] = 0;
  __syncthreads();
  int src[EPT], dst[EPT];
#pragma unroll
  for (int k = 0; k < EPT; ++k) {
    int e = base + k * 256 + t;
    if (e < E) { src[k] = ei[e]; dst[k] = ei[E + e]; }
    else if (e < Ep) { src[k] = dst[k] = e - E; }   // self-loop
    else { src[k] = -1; dst[k] = -1; }
    if (dst[k] >= 0) atomicAdd(&hist[dst[k] >> 10], 1);
  }
  __syncthreads();
  if (t < NB && hist[t] > 0) lbase[t] = atomicAdd(&bcur[t], hist[t]);
  __syncthreads();
  if (t < MAXNB) hist[t] = 0;   // reuse as local cursor
  __syncthreads();
#pragma unroll
  for (int k = 0; k < EPT; ++k) {
    if (dst[k] >= 0) {
      int b = dst[k] >> 10;
      int r = atomicAdd(&hist[b], 1);
      ebuf[(size_t)b * region + lbase[b] + r] =
          make_uint2((unsigned)src[k], (unsigned)dst[k]);
    }
  }
}

// ---- pass 2: per-bucket CSR (bucket-count scan done redundantly in-block) --
__global__ __launch_bounds__(256) void k_csr(const uint2* __restrict__ ebuf,
                                             const int* __restrict__ bcur,
                                             int* __restrict__ rowptr,
                                             int* __restrict__ colsrc,
                                             int N, int NB, int region) {
  __shared__ int cnt[NPB];
  __shared__ int lds2[256];
  __shared__ int sscan[MAXNB];
  const int b = blockIdx.x;
  const int t = threadIdx.x;
  // exclusive bucket base via in-block scan of bcur (128 entries, tiny)
  if (t < MAXNB) sscan[t] = (t < NB) ? bcur[t] : 0;
  __syncthreads();
  for (int off = 1; off < MAXNB; off <<= 1) {
    int u = (t < MAXNB && t >= off) ? sscan[t - off] : 0;
    __syncthreads();
    if (t < MAXNB) sscan[t] += u;
    __syncthreads();
  }
  const int cb = (b == 0) ? 0 : sscan[b - 1];
  if (b == 0 && t == 0) rowptr[N] = sscan[NB - 1];
  const int m = bcur[b];
  const size_t ebase = (size_t)b * region;
#pragma unroll
  for (int i = 0; i < 4; ++i) cnt[t * 4 + i] = 0;
  __syncthreads();
  for (int j = t; j < m; j += 256) {
    int d = (int)(ebuf[ebase + j].y) & (NPB - 1);
    atomicAdd(&cnt[d], 1);
  }
  __syncthreads();
  int v[4], s = 0;
#pragma unroll
  for (int i = 0; i < 4; ++i) { v[i] = cnt[t * 4 + i]; s += v[i]; }
  lds2[t] = s;
  __syncthreads();
  for (int off = 1; off < 256; off <<= 1) {
    int u = (t >= off) ? lds2[t - off] : 0;
    __syncthreads();
    lds2[t] += u;
    __syncthreads();
  }
  int e = lds2[t] - s;  // exclusive over this bucket
  const int node0 = (b << 10) + t * 4;
#pragma unroll
  for (int i = 0; i < 4; ++i) {
    cnt[t * 4 + i] = e;                       // per-node cursor start
    if (node0 + i < N) rowptr[node0 + i] = cb + e;
    e += v[i];
  }
  __syncthreads();
  for (int j = t; j < m; j += 256) {
    uint2 q = ebuf[ebase + j];
    int d = (int)q.y & (NPB - 1);
    int r = atomicAdd(&cnt[d], 1);
    colsrc[cb + r] = (int)q.x;
  }
}

// ---------------- f16 MFMA GEMM: h = A @ W, 64 rows/block ---------------------
// Fuses: fp16 feature mirror (Hh) + per-row/head attention logits (as/ad).
// A: fp32 (layer1) or fp16 (layer2). W fp32 [128][128] transposed into LDS f16.
// Wave w covers rows [w*16, w*16+16), all 128 cols = 8 tiles of 16x16, K=4x32.
template <int AFP16>
__global__ __launch_bounds__(256) void k_gemm_mfma(const void* __restrict__ Ain,
                                                   const float* __restrict__ W,
                                                   const float* __restrict__ avs,
                                                   const float* __restrict__ avd,
                                                   __half* __restrict__ Hh,
                                                   float* __restrict__ as_out,
                                                   float* __restrict__ ad_out,
                                                   int nrows) {
  __shared__ __align__(16) f16 sA[64][136];    // stride 136 halves = 272 B (16B-mult)
  __shared__ __align__(16) f16 sBT[128][136];  // W^T: [n][k]
  const int t = threadIdx.x;
  const int row0 = blockIdx.x * 64;
  // stage W^T (f16): read W[k][n..n+3] coalesced, scatter-write transpose
#pragma unroll
  for (int i = 0; i < 16; ++i) {
    int idx = (t + i * 256) * 4;
    int k = idx >> 7, n = idx & 127;
    float4 w4 = *(const float4*)&W[idx];
    sBT[n + 0][k] = (f16)w4.x;
    sBT[n + 1][k] = (f16)w4.y;
    sBT[n + 2][k] = (f16)w4.z;
    sBT[n + 3][k] = (f16)w4.w;
  }
  // stage A rows (zero-fill out-of-range)
  if (AFP16) {
    const __half* A = (const __half*)Ain + (size_t)row0 * 128;
#pragma unroll
    for (int i = 0; i < 8; ++i) {
      int idx = (t + i * 256) * 4;  // half index
      int m = idx >> 7, c = idx & 127;
      h2x2 v;
      if (row0 + m < nrows) v = *(const h2x2*)&A[idx];
      else { v.a = __floats2half2_rn(0.f, 0.f); v.b = v.a; }
      *(h2x2*)&sA[m][c] = v;
    }
  } else {
    const float* A = (const float*)Ain + (size_t)row0 * 128;
#pragma unroll
    for (int i = 0; i < 8; ++i) {
      int idx = (t + i * 256) * 4;  // float index
      int m = idx >> 7, c = idx & 127;
      float4 a4 = (row0 + m < nrows) ? *(const float4*)&A[idx]
                                     : make_float4(0.f, 0.f, 0.f, 0.f);
      h2x2 v;
      v.a = __floats2half2_rn(a4.x, a4.y);
      v.b = __floats2half2_rn(a4.z, a4.w);
      *(h2x2*)&sA[m][c] = v;
    }
  }
  __syncthreads();
  const int wv = t >> 6;
  const int l = t & 63;
  const int lm = l & 15;           // m (A-row) / n (B-col, D-col) within tile
  const int lk = (l >> 4) * 8;     // k offset within 32-chunk
  const int mw = wv * 16;          // wave row offset
  f32x4 acc[8];
#pragma unroll
  for (int tt = 0; tt < 8; ++tt) acc[tt] = (f32x4){0.f, 0.f, 0.f, 0.f};
#pragma unroll
  for (int kb = 0; kb < 4; ++kb) {
    f16x8 af = *(const f16x8*)&sA[mw + lm][kb * 32 + lk];
#pragma unroll
    for (int tt = 0; tt < 8; ++tt) {
      f16x8 bf = *(const f16x8*)&sBT[tt * 16 + lm][kb * 32 + lk];
      acc[tt] = __builtin_amdgcn_mfma_f32_16x16x32_f16(af, bf, acc[tt], 0, 0, 0);
    }
  }
  // epilogue: attention logit partials + fp16 h store
  float avst[8], avdt[8];
#pragma unroll
  for (int tt = 0; tt < 8; ++tt) {
    avst[tt] = avs[tt * 16 + lm];
    avdt[tt] = avd[tt * 16 + lm];
  }
#pragma unroll
  for (int reg = 0; reg < 4; ++reg) {
    const int row = row0 + mw + (l >> 4) * 4 + reg;
    float ps0 = acc[0][reg] * avst[0] + acc[1][reg] * avst[1];
    float ps1 = acc[2][reg] * avst[2] + acc[3][reg] * avst[3];
    float ps2 = acc[4][reg] * avst[4] + acc[5][reg] * avst[5];
    float ps3 = acc[6][reg] * avst[6] + acc[7][reg] * avst[7];
    float pd0 = acc[0][reg] * avdt[0] + acc[1][reg] * avdt[1];
    float pd1 = acc[2][reg] * avdt[2] + acc[3][reg] * avdt[3];
    float pd2 = acc[4][reg] * avdt[4] + acc[5][reg] * avdt[5];
    float pd3 = acc[6][reg] * avdt[6] + acc[7][reg] * avdt[7];
#pragma unroll
    for (int off = 1; off < 16; off <<= 1) {  // reduce cols within 16-lane group
      ps0 += __shfl_xor(ps0, off); ps1 += __shfl_xor(ps1, off);
      ps2 += __shfl_xor(ps2, off); ps3 += __shfl_xor(ps3, off);
      pd0 += __shfl_xor(pd0, off); pd1 += __shfl_xor(pd1, off);
      pd2 += __shfl_xor(pd2, off); pd3 += __shfl_xor(pd3, off);
    }
    if (row < nrows) {
      if (lm < 4) {
        float vs = lm == 0 ? ps0 : lm == 1 ? ps1 : lm == 2 ? ps2 : ps3;
        float vd = lm == 0 ? pd0 : lm == 1 ? pd1 : lm == 2 ? pd2 : pd3;
        as_out[row * 4 + lm] = vs;
        ad_out[row * 4 + lm] = vd;
      }
#pragma unroll
      for (int tt = 0; tt < 8; ++tt)
        Hh[(size_t)row * 128 + tt * 16 + lm] = __float2half(acc[tt][reg]);
    }
  }
}

// ---------------- fused softmax+aggregate; 32 lanes per node -----------------
// LAYER 1: relu(agg + b1) -> fp16 [N,128]; LAYER 2: head-mean+b2+relu+classifier
template <int LAYER>
__global__ __launch_bounds__(256) void k_agg(const int* __restrict__ rowptr,
                                             const int* __restrict__ colsrc,
                                             const float* __restrict__ as,
                                             const float* __restrict__ ad,
                                             const __half* __restrict__ Hh,
                                             const float* __restrict__ b1,
                                             const float* __restrict__ b2,
                                             const float* __restrict__ Wc,
                                             const float* __restrict__ bc,
                                             __half* __restrict__ outh,
                                             float* __restrict__ out, int n) {
  __shared__ float sbuf[8][128];
  const int slot = threadIdx.x >> 5;
  const int l = threadIdx.x & 31;
  const int node = blockIdx.x * 8 + slot;
  const bool active = node < n;
  int start = 0, end = 0;
  float4 adv = make_float4(0.f, 0.f, 0.f, 0.f);
  if (active) {
    start = rowptr[node];
    end = rowptr[node + 1];
    adv = *(const float4*)&ad[node * 4];
  }
  const int hd = l >> 3;
  const float adh = hd == 0 ? adv.x : hd == 1 ? adv.y : hd == 2 ? adv.z : adv.w;
  const int c = l * 4;
  float4 acc = make_float4(0.f, 0.f, 0.f, 0.f);
  float dsum = 0.f;
  int e = start;
  for (; e + 3 < end; e += 4) {
    int s0 = colsrc[e], s1 = colsrc[e + 1], s2 = colsrc[e + 2], s3 = colsrc[e + 3];
    float a0 = as[s0 * 4 + hd];
    float a1 = as[s1 * 4 + hd];
    float a2 = as[s2 * 4 + hd];
    float a3 = as[s3 * 4 + hd];
    h2x2 q0 = *(const h2x2*)&Hh[(size_t)s0 * 128 + c];
    h2x2 q1 = *(const h2x2*)&Hh[(size_t)s1 * 128 + c];
    h2x2 q2 = *(const h2x2*)&Hh[(size_t)s2 * 128 + c];
    h2x2 q3 = *(const h2x2*)&Hh[(size_t)s3 * 128 + c];
    float w0 = __expf(leaky02(a0 + adh));
    float w1 = __expf(leaky02(a1 + adh));
    float w2 = __expf(leaky02(a2 + adh));
    float w3 = __expf(leaky02(a3 + adh));
    dsum += w0 + w1 + w2 + w3;
    float2 f0a = __half22float2(q0.a), f0b = __half22float2(q0.b);
    float2 f1a = __half22float2(q1.a), f1b = __half22float2(q1.b);
    float2 f2a = __half22float2(q2.a), f2b = __half22float2(q2.b);
    float2 f3a = __half22float2(q3.a), f3b = __half22float2(q3.b);
    acc.x = fmaf(w0, f0a.x, acc.x); acc.y = fmaf(w0, f0a.y, acc.y);
    acc.z = fmaf(w0, f0b.x, acc.z); acc.w = fmaf(w0, f0b.y, acc.w);
    acc.x = fmaf(w1, f1a.x, acc.x); acc.y = fmaf(w1, f1a.y, acc.y);
    acc.z = fmaf(w1, f1b.x, acc.z); acc.w = fmaf(w1, f1b.y, acc.w);
    acc.x = fmaf(w2, f2a.x, acc.x); acc.y = fmaf(w2, f2a.y, acc.y);
    acc.z = fmaf(w2, f2b.x, acc.z); acc.w = fmaf(w2, f2b.y, acc.w);
    acc.x = fmaf(w3, f3a.x, acc.x); acc.y = fmaf(w3, f3a.y, acc.y);
    acc.z = fmaf(w3, f3b.x, acc.z); acc.w = fmaf(w3, f3b.y, acc.w);
  }
  for (; e < end; ++e) {
    int s0 = colsrc[e];
    float w = __expf(leaky02(as[s0 * 4 + hd] + adh));
    h2x2 q = *(const h2x2*)&Hh[(size_t)s0 * 128 + c];
    float2 fa = __half22float2(q.a), fb = __half22float2(q.b);
    dsum += w;
    acc.x = fmaf(w, fa.x, acc.x); acc.y = fmaf(w, fa.y, acc.y);
    acc.z = fmaf(w, fb.x, acc.z); acc.w = fmaf(w, fb.y, acc.w);
  }
  const float inv = dsum > 0.f ? 1.0f / dsum : 0.f;
  acc.x *= inv; acc.y *= inv; acc.z *= inv; acc.w *= inv;
  if (LAYER == 1) {
    if (active) {
      float4 bv = *(const float4*)&b1[c];
      h2x2 pk;
      pk.a = __floats2half2_rn(fmaxf(acc.x + bv.x, 0.f), fmaxf(acc.y + bv.y, 0.f));
      pk.b = __floats2half2_rn(fmaxf(acc.z + bv.z, 0.f), fmaxf(acc.w + bv.w, 0.f));
      *(h2x2*)&outh[(size_t)node * 128 + c] = pk;
    }
  } else {
    *(float4*)&sbuf[slot][c] = acc;
    __syncthreads();
    float f = 0.25f * (sbuf[slot][l] + sbuf[slot][l + 32] +
                       sbuf[slot][l + 64] + sbuf[slot][l + 96]);
    f = fmaxf(f + b2[l], 0.f);
    __syncthreads();
    sbuf[slot][l] = f;
    __syncthreads();
    if (active && l < 16) {
      float o = bc[l];
#pragma unroll
      for (int cc = 0; cc < 32; ++cc) o = fmaf(sbuf[slot][cc], Wc[cc * 16 + l], o);
      out[(size_t)node * 16 + l] = o;
    }
  }
}

// ---------------------------------------------------------------------------
extern "C" void kernel_launch(void* const* d_in, const int* in_sizes, int n_in,
                              void* d_out, int out_size, void* d_ws, size_t ws_size,
                              hipStream_t stream) {
  const float* x = (const float*)d_in[0];
  const int* ei = (const int*)d_in[1];   // [2,E] int32
  const float* W1 = (const float*)d_in[2];
  const float* a_s1 = (const float*)d_in[3];
  const float* a_d1 = (const float*)d_in[4];
  const float* b1 = (const float*)d_in[5];
  const float* W2 = (const float*)d_in[6];
  const float* a_s2 = (const float*)d_in[7];
  const float* a_d2 = (const float*)d_in[8];
  const float* b2 = (const float*)d_in[9];
  const float* Wc = (const float*)d_in[10];
  const float* bc = (const float*)d_in[11];
  float* out = (float*)d_out;

  const int N = in_sizes[0] / 128;
  const int E = in_sizes[1] / 2;
  const int Ep = E + N;
  const int NB = (N + NPB - 1) >> 10;
  const int region = Ep / NB + 4096;

  // workspace carve-up
  char* p = (char*)d_ws;
  auto align16 = [](char* q) { return (char*)(((uintptr_t)q + 15) & ~(uintptr_t)15); };
  __half* Hh = (__half*)p;   p = align16(p + sizeof(__half) * (size_t)N * 128);
  __half* x2h = (__half*)p;  p = align16(p + sizeof(__half) * (size_t)N * 128);
  float* asb = (float*)p;    p = align16(p + sizeof(float) * (size_t)N * 4);
  float* adb = (float*)p;    p = align16(p + sizeof(float) * (size_t)N * 4);
  int* rowptr = (int*)p;     p = align16(p + sizeof(int) * (size_t)(N + 1));
  int* bcur = (int*)p;       p = align16(p + sizeof(int) * MAXNB);
  int* colsrc = (int*)p;     p = align16(p + sizeof(int) * (size_t)Ep);
  uint2* ebuf = (uint2*)p;   // NB * region * 8B (~17 MB)

  hipMemsetAsync(bcur, 0, sizeof(int) * MAXNB, stream);

  k_bucketize<<<(Ep + CH - 1) / CH, 256, 0, stream>>>(ei, ebuf, bcur, E, N, NB, region);
  k_csr<<<NB, 256, 0, stream>>>(ebuf, bcur, rowptr, colsrc, N, NB, region);

  const int gblocks = (N + 63) / 64;
  k_gemm_mfma<0><<<gblocks, 256, 0, stream>>>(x, W1, a_s1, a_d1, Hh, asb, adb, N);
  k_agg<1><<<(N + 7) / 8, 256, 0, stream>>>(rowptr, colsrc, asb, adb, Hh,
                                            b1, nullptr, nullptr, nullptr, x2h, nullptr, N);
  k_gemm_mfma<1><<<gblocks, 256, 0, stream>>>(x2h, W2, a_s2, a_d2, Hh, asb, adb, N);
  k_agg<2><<<(N + 7) / 8, 256, 0, stream>>>(rowptr, colsrc, asb, adb, Hh,
                                            nullptr, b2, Wc, bc, nullptr, out, N);
}